// Round 3
// baseline (295.565 us; speedup 1.0000x reference)
//
#include <hip/hip_runtime.h>
#include <math.h>

// Shift_11261404250938: per-image shift(trunc(±10%)) + zero-fill, standardize,
// min-max normalize. Standardization cancels in the min-max step, so
// out = (shifted - min) / (max - min).
//
// R2 -> R3: manual x4 unroll of both phases so each wave keeps 4-8 float4
// loads in flight (R2 had VGPR_Count=16 => MLP depth ~1 => latency-bound at
// 2.6 TB/s). Addresses computed and loads issued for all 4 units before any
// consumption.

constexpr int kC = 3, kH = 224, kW = 224;
constexpr int kCHW = kC * kH * kW;   // 150528
constexpr int kROWS = kC * kH;       // 672
constexpr int kQPR  = kW / 4;        // 56 quads per row
constexpr int kNQ   = kROWS * kQPR;  // 37632 quads per image
constexpr int BLOCK = 1024;
constexpr int ITERS = kNQ / BLOCK;   // 36 full iterations; tail = 768 quads
constexpr int U = 4;                 // unroll factor (ITERS % U == 0)

template <int R>
__device__ __forceinline__ void phase2(const float* __restrict__ xb,
                                       float* __restrict__ ob,
                                       int sy, int sx, float mn, float inv,
                                       int tid)
{
    int it = 0;
    for (; it + U <= ITERS; it += U) {
        float4 av[U], bv[U];
        int i0[U], orow[U];
        bool rowok[U];
        #pragma unroll
        for (int u = 0; u < U; ++u) {
            const int f  = tid + (it + u) * BLOCK;
            const int rr = f / kQPR;
            const int q  = f - rr * kQPR;
            const int j  = rr % kH;
            const int c0 = rr - j;
            const int jj = j + sy;
            rowok[u] = (unsigned)jj < (unsigned)kH;
            const int jc = rowok[u] ? jj : 0;
            const float* __restrict__ src = xb + (c0 + jc) * kW;
            i0[u]   = q * 4;
            orow[u] = rr * kW;
            const int base = i0[u] + sx - R;  // multiple of 4
            int qa = base;     qa = qa < 0 ? 0 : qa; qa = qa > kW - 4 ? kW - 4 : qa;
            int qb = base + 4; qb = qb < 0 ? 0 : qb; qb = qb > kW - 4 ? kW - 4 : qb;
            av[u] = *(const float4*)(src + qa);
            bv[u] = *(const float4*)(src + qb);
        }
        #pragma unroll
        for (int u = 0; u < U; ++u) {
            const float* a = (const float*)&av[u];
            const float* b = (const float*)&bv[u];
            float sel[4];
            #pragma unroll
            for (int k = 0; k < 4; ++k)
                sel[k] = (k + R < 4) ? a[k + R] : b[k + R - 4];
            float4 o;
            float* po = (float*)&o;
            #pragma unroll
            for (int k = 0; k < 4; ++k) {
                const int s = i0[u] + k + sx;
                const float v = (rowok[u] && (unsigned)s < (unsigned)kW) ? sel[k] : 0.0f;
                po[k] = (v - mn) * inv;
            }
            *(float4*)(ob + orow[u] + i0[u]) = o;
        }
    }
    // tail: f = tid + 36*BLOCK, active for tid < 768
    {
        const int f = tid + it * BLOCK;
        if (f < kNQ) {
            const int rr = f / kQPR;
            const int q  = f - rr * kQPR;
            const int j  = rr % kH;
            const int c0 = rr - j;
            const int jj = j + sy;
            const bool rowok = (unsigned)jj < (unsigned)kH;
            const int jc = rowok ? jj : 0;
            const float* __restrict__ src = xb + (c0 + jc) * kW;
            const int i0 = q * 4;
            const int base = i0 + sx - R;
            int qa = base;     qa = qa < 0 ? 0 : qa; qa = qa > kW - 4 ? kW - 4 : qa;
            int qb = base + 4; qb = qb < 0 ? 0 : qb; qb = qb > kW - 4 ? kW - 4 : qb;
            const float4 avv = *(const float4*)(src + qa);
            const float4 bvv = *(const float4*)(src + qb);
            const float* a = (const float*)&avv;
            const float* b = (const float*)&bvv;
            float sel[4];
            #pragma unroll
            for (int k = 0; k < 4; ++k)
                sel[k] = (k + R < 4) ? a[k + R] : b[k + R - 4];
            float4 o;
            float* po = (float*)&o;
            #pragma unroll
            for (int k = 0; k < 4; ++k) {
                const int s = i0 + k + sx;
                const float v = (rowok && (unsigned)s < (unsigned)kW) ? sel[k] : 0.0f;
                po[k] = (v - mn) * inv;
            }
            *(float4*)(ob + rr * kW + i0) = o;
        }
    }
}

__global__ __launch_bounds__(BLOCK) void shift_norm(
    const float* __restrict__ x, const float* __restrict__ sfy,
    const float* __restrict__ sfx, float* __restrict__ out)
{
    const int img = blockIdx.x;
    const float* __restrict__ xb = x + (size_t)img * kCHW;
    float* __restrict__ ob = out + (size_t)img * kCHW;

    // Replicate reference fp32 order: ((f*2-1)*0.1f)*size, trunc toward zero.
    float ty = sfy[img] * 2.0f - 1.0f; ty *= 0.1f; ty *= (float)kH;
    const int sy = (int)truncf(ty);
    float tx = sfx[img] * 2.0f - 1.0f; tx *= 0.1f; tx *= (float)kW;
    const int sx = (int)truncf(tx);

    const int tid = threadIdx.x;

    // Valid input sub-rectangle (rows/cols of x that survive the shift).
    const int rlo = sy > 0 ? sy : 0;
    const int rhi = kH + (sy < 0 ? sy : 0);
    const int clo = sx > 0 ? sx : 0;
    const int chi = kW + (sx < 0 ? sx : 0);

    float vmin = INFINITY, vmax = -INFINITY;

    // Phase 1: x4-unrolled aligned float4 streaming min/max; invalid -> 0.
    int it = 0;
    for (; it + U <= ITERS; it += U) {
        float4 v[U];
        int qq[U];
        bool rok[U];
        #pragma unroll
        for (int u = 0; u < U; ++u) {
            const int f  = tid + (it + u) * BLOCK;
            const int rr = f / kQPR;
            const int q  = f - rr * kQPR;
            const int j  = rr % kH;
            rok[u] = (j >= rlo) & (j < rhi);
            qq[u]  = q * 4;
            v[u] = *(const float4*)(xb + rr * kW + qq[u]);
        }
        #pragma unroll
        for (int u = 0; u < U; ++u) {
            const float* p = (const float*)&v[u];
            #pragma unroll
            for (int k = 0; k < 4; ++k) {
                const int i = qq[u] + k;
                const float val = (rok[u] & (i >= clo) & (i < chi)) ? p[k] : 0.0f;
                vmin = fminf(vmin, val);
                vmax = fmaxf(vmax, val);
            }
        }
    }
    {   // tail: tid < 768
        const int f = tid + it * BLOCK;
        if (f < kNQ) {
            const int rr = f / kQPR;
            const int q  = f - rr * kQPR;
            const int j  = rr % kH;
            const bool rok = (j >= rlo) & (j < rhi);
            const float4 v4 = *(const float4*)(xb + rr * kW + q * 4);
            const float* p = (const float*)&v4;
            #pragma unroll
            for (int k = 0; k < 4; ++k) {
                const int i = q * 4 + k;
                const float val = (rok & (i >= clo) & (i < chi)) ? p[k] : 0.0f;
                vmin = fminf(vmin, val);
                vmax = fmaxf(vmax, val);
            }
        }
    }

    // Wave (64-lane) shuffle reduction, then cross-wave via LDS.
    #pragma unroll
    for (int off = 32; off > 0; off >>= 1) {
        vmin = fminf(vmin, __shfl_down(vmin, off));
        vmax = fmaxf(vmax, __shfl_down(vmax, off));
    }
    __shared__ float smin[BLOCK / 64], smax[BLOCK / 64];
    __shared__ float s_mn, s_inv;
    const int wave = tid >> 6, lane = tid & 63;
    if (lane == 0) { smin[wave] = vmin; smax[wave] = vmax; }
    __syncthreads();
    if (tid == 0) {
        float mn = smin[0], mx = smax[0];
        #pragma unroll
        for (int w2 = 1; w2 < BLOCK / 64; ++w2) {
            mn = fminf(mn, smin[w2]);
            mx = fmaxf(mx, smax[w2]);
        }
        s_mn = mn;
        s_inv = 1.0f / (mx - mn);
    }
    __syncthreads();
    const float mn = s_mn, inv = s_inv;

    // Phase 2: gather + normalize + aligned store; uniform rotate by sx&3.
    switch (sx & 3) {
        case 0: phase2<0>(xb, ob, sy, sx, mn, inv, tid); break;
        case 1: phase2<1>(xb, ob, sy, sx, mn, inv, tid); break;
        case 2: phase2<2>(xb, ob, sy, sx, mn, inv, tid); break;
        default: phase2<3>(xb, ob, sy, sx, mn, inv, tid); break;
    }
}

extern "C" void kernel_launch(void* const* d_in, const int* in_sizes, int n_in,
                              void* d_out, int out_size, void* d_ws, size_t ws_size,
                              hipStream_t stream) {
    const float* x  = (const float*)d_in[0];
    const float* fy = (const float*)d_in[1];
    const float* fx = (const float*)d_in[2];
    float* out = (float*)d_out;
    const int B = in_sizes[1];  // shift_fy has one element per image
    shift_norm<<<B, BLOCK, 0, stream>>>(x, fy, fx, out);
}